// Round 7
// baseline (408.582 us; speedup 1.0000x reference)
//
#include <hip/hip_runtime.h>

#define BB 8
#define NN 16384
#define CC 256
#define DD 32
#define EPSF 1e-6f

// ws layout (float units)
#define QBUF_FLOATS (2ull*BB*NN*DD)            // reserved (qbuf is bf16, uses half)
#define ACC_STRIDE 8480                         // per (s,b): KX[32][256], xsum[256], ksum0[32]
#define ACC_OFF QBUF_FLOATS
#define ACC_FLOATS (16*ACC_STRIDE)
#define FIN_OFF (ACC_OFF + ACC_FLOATS)
#define FIN_STRIDE 8480
#define WBF_OFF (FIN_OFF + 16*FIN_STRIDE)       // 32768 ushort = 16384 floats
#define MATT_OFF (WBF_OFF + 16384)              // 131072 ushort (bf16 matT [b][c][64])

typedef __attribute__((ext_vector_type(8))) short bh8;
typedef __attribute__((ext_vector_type(4))) float f4;
typedef __attribute__((ext_vector_type(2))) unsigned int u32x2;

__device__ __forceinline__ unsigned int bfp(float f) {
    unsigned int u = __float_as_uint(f);
    return (u + 0x7FFFu + ((u >> 16) & 1u)) >> 16;   // RNE fp32->bf16 bits
}
__device__ __forceinline__ float bf2f(unsigned int h) {
    return __uint_as_float(h << 16);
}

#define MFMA16 __builtin_amdgcn_mfma_f32_16x16x32_bf16

// lgkm-only barrier: LDS visibility without draining vmcnt (keeps global loads in flight)
#define LBAR() do { \
    asm volatile("s_waitcnt lgkmcnt(0)" ::: "memory"); \
    __builtin_amdgcn_s_barrier(); \
    __builtin_amdgcn_sched_barrier(0); \
} while (0)

// ---------------------------------------------------------------------------
// k0: convert the 4 projection weight matrices to bf16 once.
// ---------------------------------------------------------------------------
__global__ __launch_bounds__(256)
void k0_cvt(const float* __restrict__ Wk, const float* __restrict__ Wq,
            const float* __restrict__ Wky, const float* __restrict__ Wqy,
            unsigned short* __restrict__ wbf)
{
    int i = blockIdx.x * 256 + threadIdx.x;
    const float* p = (i < 8192) ? Wk : (i < 16384) ? Wq : (i < 24576) ? Wky : Wqy;
    wbf[i] = (unsigned short)bfp(p[i & 8191]);
}

// ---------------------------------------------------------------------------
// k1: 32-row chunks x8, double-buffered LDS, 2-deep register prefetch so
//     ~256 B/lane of global loads stay in flight across lgkm-only barriers.
//     Wave w = d-tile (w0/w1 = K halves, w2/w3 = Q halves).
//     GEMM1: D'[d][p] = W.X^T + bias (W frags in VGPRs).
//     GEMM2: KX[d][c] += K^T.X via ds_read_b64_tr_b16, counted lgkm pipeline.
// ---------------------------------------------------------------------------
__global__ __launch_bounds__(256, 4)
void k1_proj(const float* __restrict__ x, const float* __restrict__ y,
             const unsigned short* __restrict__ wbf,
             const float* __restrict__ bk, const float* __restrict__ bq,
             const float* __restrict__ bky, const float* __restrict__ bqy,
             unsigned short* __restrict__ qbuf16, float* __restrict__ acc,
             float* __restrict__ pbuf)
{
    const int b = blockIdx.y, s = blockIdx.z;
    const float* __restrict__ src = (s ? y : x) + (size_t)b * NN * CC;
    unsigned short* __restrict__ qb = qbuf16 + (size_t)(s*BB + b) * NN * DD;
    float* __restrict__ accsb = acc + (size_t)(s*BB + b) * ACC_STRIDE;
    float* __restrict__ pout = pbuf + ((size_t)((s*BB + b) * 64 + blockIdx.x)) * 8192;

    __shared__ unsigned short Xsub[2][8192];   // 2 x 16 KB subtiled bf16 (32 rows each)
    __shared__ unsigned short Ksb[1024];       // 2 KB [p][d]-subtiled bf16 K (32 p)
    __shared__ float red[4][32];               // norm partials
    __shared__ float xred[4][256];             // xsum cross-wave

    const int tid = threadIdx.x;
    const int w = tid >> 6, lane = tid & 63;
    const int l15 = lane & 15, l4 = lane >> 4;
    const int oct = lane & 31;
    const int rower = tid >> 5;                // 0..7

    // weight frags: matrix (s*2 + (w>>1)), rows 16*(w&1)+l15
    const unsigned short* __restrict__ wm =
        wbf + (size_t)(s * 2 + (w >> 1)) * 8192 + (size_t)(16 * (w & 1) + l15) * 256 + 8 * l4;
    bh8 wf[8];
    #pragma unroll
    for (int ks = 0; ks < 8; ++ks) wf[ks] = *(const bh8*)(wm + 32 * ks);
    const float* __restrict__ bp = (w < 2) ? (s ? bky : bk) : (s ? bqy : bq);
    const f4 bias4 = *(const f4*)(bp + 16 * (w & 1) + 4 * l4);

    // staging LDS byte (row r = it*8 + rower, cols oct*8..+7), it stride 4096
    const int hv = (rower >> 2) & 1;
    const int wbyte0 = (hv * 2048 + (oct >> 1) * 128 + (rower & 3) * 32 + (oct & 1) * 16) ^ (hv << 4);
    // GEMM1 B-frag: p = 16*pt + l15, c = 32ks+8l4
    int ab[2];
    #pragma unroll
    for (int pt = 0; pt < 2; ++pt) {
        int aq = 4 * pt + (l15 >> 2);
        ab[pt] = ((aq * 2048 + (l15 & 3) * 32 + (l4 & 1) * 16) ^ ((aq & 1) << 4)) + (l4 >> 1) * 128;
    }
    const unsigned xb0 = (unsigned)(uintptr_t)&Xsub[0][0];
    const unsigned kbase = (unsigned)(uintptr_t)&Ksb[0];
    const unsigned btr_rel = (unsigned)(2 * l4 * 2048 + 4 * w * 128 + l15 * 8);
    const unsigned atr = kbase + (unsigned)(2 * l4 * 256 + l15 * 8);

    f4 g2[2][4];
    #pragma unroll
    for (int dt = 0; dt < 2; ++dt)
        #pragma unroll
        for (int ct = 0; ct < 4; ++ct) g2[dt][ct] = (f4){0.f, 0.f, 0.f, 0.f};
    float xs[8];
    #pragma unroll
    for (int j = 0; j < 8; ++j) xs[j] = 0.f;
    float kreg[4] = {0.f, 0.f, 0.f, 0.f};

    const float* __restrict__ gbase = src + (size_t)(blockIdx.x * 256 + rower) * CC + oct * 8;
    float4 va[2][4], vb[2][4];

    // prologue: issue chunks 0 and 1 (16 dwordx4 loads outstanding)
    #pragma unroll
    for (int pc = 0; pc < 2; ++pc)
        #pragma unroll
        for (int it = 0; it < 4; ++it) {
            const float* g = gbase + (size_t)(pc * 32 + it * 8) * CC;
            va[pc][it] = *(const float4*)g;
            vb[pc][it] = *(const float4*)(g + 4);
        }

    #pragma unroll 2
    for (int ch = 0; ch < 8; ++ch) {
        const int cur = ch & 1;
        char* xcur = (char*)&Xsub[cur][0];

        // ---- consume regs -> pack -> LDS; then issue chunk ch+2 loads
        #pragma unroll
        for (int it = 0; it < 4; ++it) {
            float4 A = va[cur][it], B = vb[cur][it];
            xs[0] += A.x; xs[1] += A.y; xs[2] += A.z; xs[3] += A.w;
            xs[4] += B.x; xs[5] += B.y; xs[6] += B.z; xs[7] += B.w;
            uint4 pk;
            pk.x = bfp(A.x) | (bfp(A.y) << 16);
            pk.y = bfp(A.z) | (bfp(A.w) << 16);
            pk.z = bfp(B.x) | (bfp(B.y) << 16);
            pk.w = bfp(B.z) | (bfp(B.w) << 16);
            *(uint4*)(xcur + wbyte0 + it * 4096) = pk;
        }
        if (ch < 6) {
            const float* gn = gbase + (size_t)((ch + 2) * 32) * CC;
            #pragma unroll
            for (int it = 0; it < 4; ++it) {
                const float* g = gn + (size_t)(it * 8) * CC;
                va[cur][it] = *(const float4*)g;
                vb[cur][it] = *(const float4*)(g + 4);
            }
        }
        LBAR();   // S1: Xsub[cur] visible; global loads stay in flight

        // ---- GEMM1: D'[d][p] = W.X^T + bias
        f4 a1[2];
        #pragma unroll
        for (int pt = 0; pt < 2; ++pt) a1[pt] = bias4;
        #pragma unroll
        for (int ks = 0; ks < 8; ++ks) {
            #pragma unroll
            for (int pt = 0; pt < 2; ++pt) {
                bh8 xbv = *(const bh8*)(xcur + ab[pt] + ks * 256);
                a1[pt] = MFMA16(wf[ks], xbv, a1[pt], 0, 0, 0);
            }
        }

        // ---- norm partials
        #pragma unroll
        for (int pt = 0; pt < 2; ++pt) {
            float ssv = a1[pt][0]*a1[pt][0] + a1[pt][1]*a1[pt][1]
                      + a1[pt][2]*a1[pt][2] + a1[pt][3]*a1[pt][3];
            ssv += __shfl_xor(ssv, 16);
            ssv += __shfl_xor(ssv, 32);
            if (l4 == 0) red[w][16 * pt + l15] = ssv;
        }
        LBAR();   // S2: red visible

        if (w < 2) {
            #pragma unroll
            for (int pt = 0; pt < 2; ++pt) {
                int p = 16 * pt + l15;
                float n = rsqrtf(red[0][p] + red[1][p]);
                float k0 = a1[pt][0]*n, k1 = a1[pt][1]*n, k2 = a1[pt][2]*n, k3 = a1[pt][3]*n;
                kreg[0] += k0; kreg[1] += k1; kreg[2] += k2; kreg[3] += k3;
                unsigned lo = bfp(k0) | (bfp(k1) << 16);
                unsigned hi = bfp(k2) | (bfp(k3) << 16);
                *(uint2*)((char*)Ksb + (p >> 2) * 256 + (w & 1) * 128 + (p & 3) * 32 + 8 * l4)
                    = make_uint2(lo, hi);
            }
        } else {
            #pragma unroll
            for (int pt = 0; pt < 2; ++pt) {
                int p = 16 * pt + l15;
                float n = rsqrtf(red[2][p] + red[3][p]);
                unsigned lo = bfp(a1[pt][0]*n) | (bfp(a1[pt][1]*n) << 16);
                unsigned hi = bfp(a1[pt][2]*n) | (bfp(a1[pt][3]*n) << 16);
                *(uint2*)(qb + (size_t)(blockIdx.x*256 + ch*32 + p) * DD + 16 * (w & 1) + 4 * l4)
                    = make_uint2(lo, hi);
            }
        }
        LBAR();   // S3: Ksb visible

        // ---- GEMM2: KX += K^T.X via tr-reads, counted lgkm pipeline
        {
            const unsigned kb = xb0 + (unsigned)(cur * 16384) + btr_rel;
            u32x2 ta0, ta1, ta2, ta3, tb0, tb1, tb2, tb3, tb4, tb5, tb6, tb7;
            asm volatile("ds_read_b64_tr_b16 %0, %1" : "=v"(ta0) : "v"(atr));
            asm volatile("ds_read_b64_tr_b16 %0, %1" : "=v"(ta1) : "v"(atr + 256u));
            asm volatile("ds_read_b64_tr_b16 %0, %1" : "=v"(ta2) : "v"(atr + 128u));
            asm volatile("ds_read_b64_tr_b16 %0, %1" : "=v"(ta3) : "v"(atr + 384u));
            asm volatile("ds_read_b64_tr_b16 %0, %1" : "=v"(tb0) : "v"(kb));
            asm volatile("ds_read_b64_tr_b16 %0, %1" : "=v"(tb1) : "v"((kb + 2048u) ^ 16u));
            asm volatile("ds_read_b64_tr_b16 %0, %1" : "=v"(tb2) : "v"(kb + 128u));
            asm volatile("ds_read_b64_tr_b16 %0, %1" : "=v"(tb3) : "v"((kb + 2176u) ^ 16u));
            asm volatile("ds_read_b64_tr_b16 %0, %1" : "=v"(tb4) : "v"(kb + 256u));
            asm volatile("ds_read_b64_tr_b16 %0, %1" : "=v"(tb5) : "v"((kb + 2304u) ^ 16u));
            asm volatile("ds_read_b64_tr_b16 %0, %1" : "=v"(tb6) : "v"(kb + 384u));
            asm volatile("ds_read_b64_tr_b16 %0, %1" : "=v"(tb7) : "v"((kb + 2432u) ^ 16u));
            asm volatile("s_waitcnt lgkmcnt(8)" ::: "memory");
            __builtin_amdgcn_sched_barrier(0);
            union { unsigned u[4]; bh8 v; } A0, A1;
            A0.u[0] = ta0[0]; A0.u[1] = ta0[1]; A0.u[2] = ta1[0]; A0.u[3] = ta1[1];
            A1.u[0] = ta2[0]; A1.u[1] = ta2[1]; A1.u[2] = ta3[0]; A1.u[3] = ta3[1];
            asm volatile("s_waitcnt lgkmcnt(6)" ::: "memory");
            __builtin_amdgcn_sched_barrier(0);
            {
                union { unsigned u[4]; bh8 v; } Bc;
                Bc.u[0] = tb0[0]; Bc.u[1] = tb0[1]; Bc.u[2] = tb1[0]; Bc.u[3] = tb1[1];
                g2[0][0] = MFMA16(A0.v, Bc.v, g2[0][0], 0, 0, 0);
                g2[1][0] = MFMA16(A1.v, Bc.v, g2[1][0], 0, 0, 0);
            }
            asm volatile("s_waitcnt lgkmcnt(4)" ::: "memory");
            __builtin_amdgcn_sched_barrier(0);
            {
                union { unsigned u[4]; bh8 v; } Bc;
                Bc.u[0] = tb2[0]; Bc.u[1] = tb2[1]; Bc.u[2] = tb3[0]; Bc.u[3] = tb3[1];
                g2[0][1] = MFMA16(A0.v, Bc.v, g2[0][1], 0, 0, 0);
                g2[1][1] = MFMA16(A1.v, Bc.v, g2[1][1], 0, 0, 0);
            }
            asm volatile("s_waitcnt lgkmcnt(2)" ::: "memory");
            __builtin_amdgcn_sched_barrier(0);
            {
                union { unsigned u[4]; bh8 v; } Bc;
                Bc.u[0] = tb4[0]; Bc.u[1] = tb4[1]; Bc.u[2] = tb5[0]; Bc.u[3] = tb5[1];
                g2[0][2] = MFMA16(A0.v, Bc.v, g2[0][2], 0, 0, 0);
                g2[1][2] = MFMA16(A1.v, Bc.v, g2[1][2], 0, 0, 0);
            }
            asm volatile("s_waitcnt lgkmcnt(0)" ::: "memory");
            __builtin_amdgcn_sched_barrier(0);
            {
                union { unsigned u[4]; bh8 v; } Bc;
                Bc.u[0] = tb6[0]; Bc.u[1] = tb6[1]; Bc.u[2] = tb7[0]; Bc.u[3] = tb7[1];
                g2[0][3] = MFMA16(A0.v, Bc.v, g2[0][3], 0, 0, 0);
                g2[1][3] = MFMA16(A1.v, Bc.v, g2[1][3], 0, 0, 0);
            }
        }
    }

    // ---- epilogue
    #pragma unroll
    for (int dt = 0; dt < 2; ++dt)
        #pragma unroll
        for (int ct = 0; ct < 4; ++ct)
            #pragma unroll
            for (int r = 0; r < 4; ++r)
                pout[(16 * dt + 4 * l4 + r) * 256 + 64 * w + 16 * ct + l15] = g2[dt][ct][r];

    #pragma unroll
    for (int j = 0; j < 8; ++j) xs[j] += __shfl_xor(xs[j], 32);
    if ((lane >> 5) == 0) {
        #pragma unroll
        for (int j = 0; j < 8; ++j) xred[w][oct * 8 + j] = xs[j];
    }
    __syncthreads();
    {
        float v = xred[0][tid] + xred[1][tid] + xred[2][tid] + xred[3][tid];
        atomicAdd(accsb + 8192 + tid, v);
    }
    if (w < 2) {
        #pragma unroll
        for (int r = 0; r < 4; ++r) {
            float v = kreg[r];
            v += __shfl_xor(v, 1); v += __shfl_xor(v, 2);
            v += __shfl_xor(v, 4); v += __shfl_xor(v, 8);
            if (l15 == 0) atomicAdd(accsb + 8448 + 16 * (w & 1) + 4 * l4 + r, v);
        }
    }
}

// ---------------------------------------------------------------------------
// k2a: reduce 64 per-block KX partials -> acc
// ---------------------------------------------------------------------------
__global__ __launch_bounds__(256)
void k2a_reduce(const float* __restrict__ pbuf, float* __restrict__ acc)
{
    const int b = blockIdx.x, s = blockIdx.y, cs = blockIdx.z;
    const float* __restrict__ p = pbuf + (size_t)(s*BB + b) * 64 * 8192;
    float* __restrict__ a = acc + (size_t)(s*BB + b) * ACC_STRIDE;
    const int d = threadIdx.x >> 3, c = cs * 32 + (threadIdx.x & 7) * 4;
    f4 v = (f4){0.f, 0.f, 0.f, 0.f};
    for (int j = 0; j < 64; ++j)
        v += *(const f4*)(p + (size_t)j * 8192 + d * 256 + c);
    *(f4*)(a + d * 256 + c) = v;
}

// ---------------------------------------------------------------------------
// k2: finalize per (b,s): mat = KX @ Wv^T + ksum0 (x) bv ; vsum = Wv@xsum + N*bv.
//     Also emits matT bf16 [b][c][64] (k = s*32+d) for k3's MFMA A-frags.
// ---------------------------------------------------------------------------
__global__ __launch_bounds__(256, 2)
void k2_finalize(const float* __restrict__ Wv, const float* __restrict__ bv,
                 const float* __restrict__ Wvy, const float* __restrict__ bvy,
                 const float* __restrict__ acc, float* __restrict__ fin,
                 unsigned short* __restrict__ matT)
{
    const int b = blockIdx.x, s = blockIdx.y;
    const float* __restrict__ Wv_ = s ? Wvy : Wv;
    const float* __restrict__ bv_ = s ? bvy : bv;
    const float* __restrict__ a = acc + (size_t)(s*BB + b) * ACC_STRIDE;
    float* __restrict__ f = fin + (size_t)(s*BB + b) * FIN_STRIDE;
    unsigned short* __restrict__ mt = matT + (size_t)b * 16384;

    __shared__ float KXt[256][36];
    __shared__ float xsh[256];
    __shared__ float ks0[32];

    const int tid = threadIdx.x;
    for (int d = 0; d < 32; ++d) KXt[tid][d] = a[d*256 + tid];
    xsh[tid] = a[8192 + tid];
    if (tid < 32) { float v = a[8448 + tid]; ks0[tid] = v; f[8448 + tid] = v + EPSF; }
    __syncthreads();

    const int dh = tid >> 7;
    const int c0 = (tid & 127) * 2;
    float macc[16][2];
    #pragma unroll
    for (int i = 0; i < 16; ++i) { macc[i][0]=0.f; macc[i][1]=0.f; }
    float v0 = 0.f, v1 = 0.f;

    for (int k4 = 0; k4 < 256; k4 += 4) {
        float4 wa = *(const float4*)(Wv_ + (size_t)c0*256 + k4);
        float4 wb = *(const float4*)(Wv_ + (size_t)(c0+1)*256 + k4);
        float4 xv = *(const float4*)&xsh[k4];
        v0 += wa.x*xv.x + wa.y*xv.y + wa.z*xv.z + wa.w*xv.w;
        v1 += wb.x*xv.x + wb.y*xv.y + wb.z*xv.z + wb.w*xv.w;
        #pragma unroll
        for (int u = 0; u < 4; ++u) {
            float wau = (u==0)?wa.x:(u==1)?wa.y:(u==2)?wa.z:wa.w;
            float wbu = (u==0)?wb.x:(u==1)?wb.y:(u==2)?wb.z:wb.w;
            #pragma unroll
            for (int i4 = 0; i4 < 16; i4 += 4) {
                float4 kxv = *(const float4*)&KXt[k4+u][dh*16 + i4];
                macc[i4+0][0] += kxv.x*wau; macc[i4+0][1] += kxv.x*wbu;
                macc[i4+1][0] += kxv.y*wau; macc[i4+1][1] += kxv.y*wbu;
                macc[i4+2][0] += kxv.z*wau; macc[i4+2][1] += kxv.z*wbu;
                macc[i4+3][0] += kxv.w*wau; macc[i4+3][1] += kxv.w*wbu;
            }
        }
    }
    float bvc0 = bv_[c0], bvc1 = bv_[c0+1];
    if (dh == 0) {
        f[8192 + c0]     = v0 + (float)NN * bvc0;
        f[8192 + c0 + 1] = v1 + (float)NN * bvc1;
    }
    union { unsigned short h[16]; uint4 q[2]; } r0u, r1u;
    #pragma unroll
    for (int i = 0; i < 16; ++i) {
        int d = dh*16 + i;
        float m0v = macc[i][0] + ks0[d]*bvc0;
        float m1v = macc[i][1] + ks0[d]*bvc1;
        f[d*256 + c0]     = m0v;
        f[d*256 + c0 + 1] = m1v;
        r0u.h[i] = (unsigned short)bfp(m0v);
        r1u.h[i] = (unsigned short)bfp(m1v);
    }
    const int kk = s * 32 + dh * 16;
    *(uint4*)(mt + (size_t)c0 * 64 + kk)           = r0u.q[0];
    *(uint4*)(mt + (size_t)c0 * 64 + kk + 8)       = r0u.q[1];
    *(uint4*)(mt + (size_t)(c0+1) * 64 + kk)       = r1u.q[0];
    *(uint4*)(mt + (size_t)(c0+1) * 64 + kk + 8)   = r1u.q[1];
}

// ---------------------------------------------------------------------------
// k3: MFMA output kernel. Per block: batch b, 32 positions, both streams.
//   Atb[r][k] bf16 in LDS (r=64: 32 x-rows + 32 y-rows; k=64), XOR-swizzled.
//   A-frags read directly from global matT (L2-hot, 32 KB per batch).
//   D[c][r] = sum_k matT[c][k]*Atb[r][k]; epilogue adds sv[r]*vs[str][c].
// ---------------------------------------------------------------------------
__global__ __launch_bounds__(256, 4)
void k3_output(const unsigned short* __restrict__ qbuf16, const float* __restrict__ fin,
               const unsigned short* __restrict__ matT,
               const float* __restrict__ g_gamma, const float* __restrict__ g_gammay,
               const float* __restrict__ g_gammacx, const float* __restrict__ g_gammacy,
               const float* __restrict__ g_wx1, const float* __restrict__ g_wx2,
               const float* __restrict__ g_wy1, const float* __restrict__ g_wy2,
               float* __restrict__ out)
{
    const int b = blockIdx.y;
    const int p0 = blockIdx.x * 32;
    const float* __restrict__ fx_ = fin + (size_t)(0*BB + b) * FIN_STRIDE;
    const float* __restrict__ fy_ = fin + (size_t)(1*BB + b) * FIN_STRIDE;

    __shared__ unsigned short Atb[64 * 64];   // 8 KB
    __shared__ float vs[2][256];
    __shared__ float sv[64];
    __shared__ float ksl[2][32];

    const int tid = threadIdx.x;
    if (tid < 64) ksl[tid >> 5][tid & 31] = ((tid < 32) ? fx_ : fy_)[8448 + (tid & 31)];
    vs[0][tid] = fx_[8192 + tid];
    vs[1][tid] = fy_[8192 + tid];
    __syncthreads();

    // coef + Atb rows (tid < 64: str=tid>>5, position p0+(tid&31))
    if (tid < 64) {
        const int str = tid >> 5;
        const int p = p0 + (tid & 31);
        const uint4* __restrict__ qp = (const uint4*)(qbuf16 + ((size_t)(str*BB + b) * NN + p) * DD);
        float q[32];
        float ss = 0.f;
        #pragma unroll
        for (int m = 0; m < 4; ++m) {
            uint4 u = qp[m];
            unsigned uu[4] = {u.x, u.y, u.z, u.w};
            #pragma unroll
            for (int j = 0; j < 4; ++j) {
                float lo = bf2f(uu[j] & 0xFFFFu), hi = bf2f(uu[j] >> 16);
                q[m*8 + 2*j] = lo; q[m*8 + 2*j + 1] = hi;
                ss += lo*lo + hi*hi;
            }
        }
        float qn = rsqrtf(ss);
        float dK = 0.f, dKy = 0.f;
        #pragma unroll
        for (int d = 0; d < 32; ++d) { dK += q[d]*ksl[0][d]; dKy += q[d]*ksl[1][d]; }
        dK *= qn; dKy *= qn;
        float clo, chi, svr;
        if (str == 0) {
            float t1 = 1.f / ((float)NN + dK);
            float t2 = 1.f / ((float)NN + dKy);
            float a1c = g_gamma[0]   * g_wx1[0] * t1;
            float a2c = g_gammacx[0] * g_wx2[0] * t2;
            clo = a1c * qn; chi = a2c * qn; svr = a1c + a2c;
        } else {
            float ty1 = 1.f / ((float)NN + dKy);
            float ty2 = 1.f / ((float)NN + dK);
            float b1c = g_gammay[0]  * g_wy1[0] * ty1;
            float b2c = g_gammacy[0] * g_wy2[0] * ty2;
            clo = b2c * qn; chi = b1c * qn; svr = b1c + b2c;
        }
        sv[tid] = svr;
        #pragma unroll
        for (int g = 0; g < 8; ++g) {
            float m0 = (g < 4) ? clo : chi;
            const float* qq = q + (g & 3) * 8;
            uint4 pk;
            pk.x = bfp(m0*qq[0]) | (bfp(m0*qq[1]) << 16);
            pk.y = bfp(m0*qq[2]) | (bfp(m0*qq[3]) << 16);
            pk.z = bfp(m0*qq[4]) | (bfp(m0*qq[5]) << 16);
            pk.w = bfp(m0*qq[6]) | (bfp(m0*qq[7]) << 16);
            unsigned off = (unsigned)(tid * 128 + g * 16) ^ (unsigned)((tid & 7) << 4);
            *(uint4*)((char*)Atb + off) = pk;
        }
    }
    __syncthreads();

    // ---- MFMA: wave w -> r-tile w (r = w*16+l15); 16 ctiles x 2 ksteps
    const int w = tid >> 6, lane = tid & 63;
    const int l15 = lane & 15, l4 = lane >> 4;
    const int r = w * 16 + l15;
    const unsigned short* __restrict__ mb = matT + (size_t)b * 16384;
    f4 accv[16];
    #pragma unroll
    for (int ct = 0; ct < 16; ++ct) accv[ct] = (f4){0.f, 0.f, 0.f, 0.f};

    #pragma unroll
    for (int kstep = 0; kstep < 2; ++kstep) {
        unsigned boff = (unsigned)(r * 128 + kstep * 64 + l4 * 16) ^ (unsigned)((r & 7) << 4);
        bh8 bfr = *(const bh8*)((const char*)Atb + boff);
        #pragma unroll
        for (int ct = 0; ct < 16; ++ct) {
            bh8 afr = *(const bh8*)(mb + (size_t)(ct * 16 + l15) * 64 + kstep * 32 + l4 * 8);
            accv[ct] = MFMA16(afr, bfr, accv[ct], 0, 0, 0);
        }
    }

    // ---- epilogue: add sv[r]*vs and store float4 (lane holds 4 consecutive c)
    const int str = w >> 1;
    const int prow = (w & 1) * 16 + l15;
    float* __restrict__ op = out + (size_t)str * BB * NN * CC + ((size_t)b * NN + p0 + prow) * CC;
    const float svr = sv[r];
    #pragma unroll
    for (int ct = 0; ct < 16; ++ct) {
        int c0 = ct * 16 + 4 * l4;
        float4 vsv = *(const float4*)&vs[str][c0];
        float4 o = make_float4(accv[ct][0] + svr*vsv.x, accv[ct][1] + svr*vsv.y,
                               accv[ct][2] + svr*vsv.z, accv[ct][3] + svr*vsv.w);
        *(float4*)(op + c0) = o;
    }
}

extern "C" void kernel_launch(void* const* d_in, const int* in_sizes, int n_in,
                              void* d_out, int out_size, void* d_ws, size_t ws_size,
                              hipStream_t stream)
{
    (void)in_sizes; (void)n_in; (void)out_size; (void)ws_size;
    const float* x   = (const float*)d_in[0];
    const float* y   = (const float*)d_in[1];
    const float* Wq  = (const float*)d_in[2];
    const float* bq  = (const float*)d_in[3];
    const float* Wk  = (const float*)d_in[4];
    const float* bk  = (const float*)d_in[5];
    const float* Wv  = (const float*)d_in[6];
    const float* bv  = (const float*)d_in[7];
    const float* Wqy = (const float*)d_in[8];
    const float* bqy = (const float*)d_in[9];
    const float* Wky = (const float*)d_in[10];
    const float* bky = (const float*)d_in[11];
    const float* Wvy = (const float*)d_in[12];
    const float* bvy = (const float*)d_in[13];

    float* ws   = (float*)d_ws;
    unsigned short* qbuf16 = (unsigned short*)ws;
    float* acc  = ws + ACC_OFF;
    float* fin  = ws + FIN_OFF;
    unsigned short* wbf  = (unsigned short*)(ws + WBF_OFF);
    unsigned short* matT = (unsigned short*)(ws + MATT_OFF);
    float* pbuf = (float*)d_out;    // scratch: fully consumed by k2a before k3 overwrites

    k0_cvt<<<128, 256, 0, stream>>>(Wk, Wq, Wky, Wqy, wbf);
    hipMemsetAsync(acc, 0, ACC_FLOATS * sizeof(float), stream);

    k1_proj<<<dim3(64, BB, 2), 256, 0, stream>>>(x, y, wbf, bk, bq, bky, bqy, qbuf16, acc, pbuf);
    k2a_reduce<<<dim3(BB, 2, 8), 256, 0, stream>>>(pbuf, acc);
    k2_finalize<<<dim3(BB, 2), 256, 0, stream>>>(Wv, bv, Wvy, bvy, acc, fin, matT);
    k3_output<<<dim3(NN/32, BB), 256, 0, stream>>>(qbuf16, fin, matT,
        (const float*)d_in[14], (const float*)d_in[15], (const float*)d_in[16], (const float*)d_in[17],
        (const float*)d_in[18], (const float*)d_in[19], (const float*)d_in[20], (const float*)d_in[21],
        (float*)d_out);
}

// Round 8
// 347.727 us; speedup vs baseline: 1.1750x; 1.1750x over previous
//
#include <hip/hip_runtime.h>

#define BB 8
#define NN 16384
#define CC 256
#define DD 32
#define EPSF 1e-6f

// ws layout (float units)
#define QBUF_FLOATS (2ull*BB*NN*DD)            // reserved (qbuf is bf16, uses half)
#define ACC_STRIDE 8480                         // per (s,b): KX[32][256], xsum[256], ksum0[32]
#define ACC_OFF QBUF_FLOATS
#define ACC_FLOATS (16*ACC_STRIDE)
#define FIN_OFF (ACC_OFF + ACC_FLOATS)
#define FIN_STRIDE 8480
#define WBF_OFF (FIN_OFF + 16*FIN_STRIDE)       // 32768 ushort = 16384 floats
#define MATT_OFF (WBF_OFF + 16384)              // 131072 ushort (bf16 matT [b][c][64])

typedef __attribute__((ext_vector_type(8))) short bh8;
typedef __attribute__((ext_vector_type(4))) float f4;
typedef __attribute__((ext_vector_type(2))) unsigned int u32x2;

__device__ __forceinline__ unsigned int bfp(float f) {
    unsigned int u = __float_as_uint(f);
    return (u + 0x7FFFu + ((u >> 16) & 1u)) >> 16;   // RNE fp32->bf16 bits
}
__device__ __forceinline__ float bf2f(unsigned int h) {
    return __uint_as_float(h << 16);
}

#define MFMA16 __builtin_amdgcn_mfma_f32_16x16x32_bf16

// lgkm-only barrier: LDS visibility without draining vmcnt (keeps global loads in flight)
#define LBAR() do { \
    asm volatile("s_waitcnt lgkmcnt(0)" ::: "memory"); \
    __builtin_amdgcn_s_barrier(); \
    __builtin_amdgcn_sched_barrier(0); \
} while (0)

// ---------------------------------------------------------------------------
// k0: convert the 4 projection weight matrices to bf16 once.
// ---------------------------------------------------------------------------
__global__ __launch_bounds__(256)
void k0_cvt(const float* __restrict__ Wk, const float* __restrict__ Wq,
            const float* __restrict__ Wky, const float* __restrict__ Wqy,
            unsigned short* __restrict__ wbf)
{
    int i = blockIdx.x * 256 + threadIdx.x;
    const float* p = (i < 8192) ? Wk : (i < 16384) ? Wq : (i < 24576) ? Wky : Wqy;
    wbf[i] = (unsigned short)bfp(p[i & 8191]);
}

// ---------------------------------------------------------------------------
// k1: 32-row chunks x8, double-buffered LDS, 2-deep register prefetch
//     (~256 B/lane in flight) at launch_bounds(256,3) -> VGPR cap 170, NO SPILL.
//     Wave w = d-tile (w0/w1 = K halves, w2/w3 = Q halves).
//     GEMM1: D'[d][p] = W.X^T + bias (W frags in VGPRs).
//     GEMM2: KX[d][c] += K^T.X via ds_read_b64_tr_b16, counted lgkm pipeline.
// ---------------------------------------------------------------------------
__global__ __launch_bounds__(256, 3)
void k1_proj(const float* __restrict__ x, const float* __restrict__ y,
             const unsigned short* __restrict__ wbf,
             const float* __restrict__ bk, const float* __restrict__ bq,
             const float* __restrict__ bky, const float* __restrict__ bqy,
             unsigned short* __restrict__ qbuf16, float* __restrict__ acc,
             float* __restrict__ pbuf)
{
    const int b = blockIdx.y, s = blockIdx.z;
    const float* __restrict__ src = (s ? y : x) + (size_t)b * NN * CC;
    unsigned short* __restrict__ qb = qbuf16 + (size_t)(s*BB + b) * NN * DD;
    float* __restrict__ accsb = acc + (size_t)(s*BB + b) * ACC_STRIDE;
    float* __restrict__ pout = pbuf + ((size_t)((s*BB + b) * 64 + blockIdx.x)) * 8192;

    __shared__ unsigned short Xsub[2][8192];   // 2 x 16 KB subtiled bf16 (32 rows each)
    __shared__ unsigned short Ksb[1024];       // 2 KB [p][d]-subtiled bf16 K (32 p)
    __shared__ float red[4][32];               // norm partials
    __shared__ float xred[4][256];             // xsum cross-wave

    const int tid = threadIdx.x;
    const int w = tid >> 6, lane = tid & 63;
    const int l15 = lane & 15, l4 = lane >> 4;
    const int oct = lane & 31;
    const int rower = tid >> 5;                // 0..7

    // weight frags: matrix (s*2 + (w>>1)), rows 16*(w&1)+l15
    const unsigned short* __restrict__ wm =
        wbf + (size_t)(s * 2 + (w >> 1)) * 8192 + (size_t)(16 * (w & 1) + l15) * 256 + 8 * l4;
    bh8 wf[8];
    #pragma unroll
    for (int ks = 0; ks < 8; ++ks) wf[ks] = *(const bh8*)(wm + 32 * ks);
    const float* __restrict__ bp = (w < 2) ? (s ? bky : bk) : (s ? bqy : bq);
    const f4 bias4 = *(const f4*)(bp + 16 * (w & 1) + 4 * l4);

    // staging LDS byte (row r = it*8 + rower, cols oct*8..+7), it stride 4096
    const int hv = (rower >> 2) & 1;
    const int wbyte0 = (hv * 2048 + (oct >> 1) * 128 + (rower & 3) * 32 + (oct & 1) * 16) ^ (hv << 4);
    // GEMM1 B-frag: p = 16*pt + l15, c = 32ks+8l4
    int ab[2];
    #pragma unroll
    for (int pt = 0; pt < 2; ++pt) {
        int aq = 4 * pt + (l15 >> 2);
        ab[pt] = ((aq * 2048 + (l15 & 3) * 32 + (l4 & 1) * 16) ^ ((aq & 1) << 4)) + (l4 >> 1) * 128;
    }
    const unsigned xb0 = (unsigned)(uintptr_t)&Xsub[0][0];
    const unsigned kbase = (unsigned)(uintptr_t)&Ksb[0];
    const unsigned btr_rel = (unsigned)(2 * l4 * 2048 + 4 * w * 128 + l15 * 8);
    const unsigned atr = kbase + (unsigned)(2 * l4 * 256 + l15 * 8);

    f4 g2[2][4];
    #pragma unroll
    for (int dt = 0; dt < 2; ++dt)
        #pragma unroll
        for (int ct = 0; ct < 4; ++ct) g2[dt][ct] = (f4){0.f, 0.f, 0.f, 0.f};
    float xs[8];
    #pragma unroll
    for (int j = 0; j < 8; ++j) xs[j] = 0.f;
    float kreg[4] = {0.f, 0.f, 0.f, 0.f};

    const float* __restrict__ gbase = src + (size_t)(blockIdx.x * 256 + rower) * CC + oct * 8;
    float4 va[2][4], vb[2][4];

    // prologue: issue chunks 0 and 1 (16 dwordx4 loads outstanding)
    #pragma unroll
    for (int pc = 0; pc < 2; ++pc)
        #pragma unroll
        for (int it = 0; it < 4; ++it) {
            const float* g = gbase + (size_t)(pc * 32 + it * 8) * CC;
            va[pc][it] = *(const float4*)g;
            vb[pc][it] = *(const float4*)(g + 4);
        }

    #pragma unroll 2
    for (int ch = 0; ch < 8; ++ch) {
        const int cur = ch & 1;
        char* xcur = (char*)&Xsub[cur][0];

        // ---- consume regs -> pack -> LDS; then issue chunk ch+2 loads
        #pragma unroll
        for (int it = 0; it < 4; ++it) {
            float4 A = va[cur][it], B = vb[cur][it];
            xs[0] += A.x; xs[1] += A.y; xs[2] += A.z; xs[3] += A.w;
            xs[4] += B.x; xs[5] += B.y; xs[6] += B.z; xs[7] += B.w;
            uint4 pk;
            pk.x = bfp(A.x) | (bfp(A.y) << 16);
            pk.y = bfp(A.z) | (bfp(A.w) << 16);
            pk.z = bfp(B.x) | (bfp(B.y) << 16);
            pk.w = bfp(B.z) | (bfp(B.w) << 16);
            *(uint4*)(xcur + wbyte0 + it * 4096) = pk;
        }
        if (ch < 6) {
            const float* gn = gbase + (size_t)((ch + 2) * 32) * CC;
            #pragma unroll
            for (int it = 0; it < 4; ++it) {
                const float* g = gn + (size_t)(it * 8) * CC;
                va[cur][it] = *(const float4*)g;
                vb[cur][it] = *(const float4*)(g + 4);
            }
        }
        LBAR();   // S1: Xsub[cur] visible; global loads stay in flight

        // ---- GEMM1: D'[d][p] = W.X^T + bias
        f4 a1[2];
        #pragma unroll
        for (int pt = 0; pt < 2; ++pt) a1[pt] = bias4;
        #pragma unroll
        for (int ks = 0; ks < 8; ++ks) {
            #pragma unroll
            for (int pt = 0; pt < 2; ++pt) {
                bh8 xbv = *(const bh8*)(xcur + ab[pt] + ks * 256);
                a1[pt] = MFMA16(wf[ks], xbv, a1[pt], 0, 0, 0);
            }
        }

        // ---- norm partials
        #pragma unroll
        for (int pt = 0; pt < 2; ++pt) {
            float ssv = a1[pt][0]*a1[pt][0] + a1[pt][1]*a1[pt][1]
                      + a1[pt][2]*a1[pt][2] + a1[pt][3]*a1[pt][3];
            ssv += __shfl_xor(ssv, 16);
            ssv += __shfl_xor(ssv, 32);
            if (l4 == 0) red[w][16 * pt + l15] = ssv;
        }
        LBAR();   // S2: red visible

        if (w < 2) {
            #pragma unroll
            for (int pt = 0; pt < 2; ++pt) {
                int p = 16 * pt + l15;
                float n = rsqrtf(red[0][p] + red[1][p]);
                float k0 = a1[pt][0]*n, k1 = a1[pt][1]*n, k2 = a1[pt][2]*n, k3 = a1[pt][3]*n;
                kreg[0] += k0; kreg[1] += k1; kreg[2] += k2; kreg[3] += k3;
                unsigned lo = bfp(k0) | (bfp(k1) << 16);
                unsigned hi = bfp(k2) | (bfp(k3) << 16);
                *(uint2*)((char*)Ksb + (p >> 2) * 256 + (w & 1) * 128 + (p & 3) * 32 + 8 * l4)
                    = make_uint2(lo, hi);
            }
        } else {
            #pragma unroll
            for (int pt = 0; pt < 2; ++pt) {
                int p = 16 * pt + l15;
                float n = rsqrtf(red[2][p] + red[3][p]);
                unsigned lo = bfp(a1[pt][0]*n) | (bfp(a1[pt][1]*n) << 16);
                unsigned hi = bfp(a1[pt][2]*n) | (bfp(a1[pt][3]*n) << 16);
                *(uint2*)(qb + (size_t)(blockIdx.x*256 + ch*32 + p) * DD + 16 * (w & 1) + 4 * l4)
                    = make_uint2(lo, hi);
            }
        }
        LBAR();   // S3: Ksb visible

        // ---- GEMM2: KX += K^T.X via tr-reads, counted lgkm pipeline
        {
            const unsigned kb = xb0 + (unsigned)(cur * 16384) + btr_rel;
            u32x2 ta0, ta1, ta2, ta3, tb0, tb1, tb2, tb3, tb4, tb5, tb6, tb7;
            asm volatile("ds_read_b64_tr_b16 %0, %1" : "=v"(ta0) : "v"(atr));
            asm volatile("ds_read_b64_tr_b16 %0, %1" : "=v"(ta1) : "v"(atr + 256u));
            asm volatile("ds_read_b64_tr_b16 %0, %1" : "=v"(ta2) : "v"(atr + 128u));
            asm volatile("ds_read_b64_tr_b16 %0, %1" : "=v"(ta3) : "v"(atr + 384u));
            asm volatile("ds_read_b64_tr_b16 %0, %1" : "=v"(tb0) : "v"(kb));
            asm volatile("ds_read_b64_tr_b16 %0, %1" : "=v"(tb1) : "v"((kb + 2048u) ^ 16u));
            asm volatile("ds_read_b64_tr_b16 %0, %1" : "=v"(tb2) : "v"(kb + 128u));
            asm volatile("ds_read_b64_tr_b16 %0, %1" : "=v"(tb3) : "v"((kb + 2176u) ^ 16u));
            asm volatile("ds_read_b64_tr_b16 %0, %1" : "=v"(tb4) : "v"(kb + 256u));
            asm volatile("ds_read_b64_tr_b16 %0, %1" : "=v"(tb5) : "v"((kb + 2304u) ^ 16u));
            asm volatile("ds_read_b64_tr_b16 %0, %1" : "=v"(tb6) : "v"(kb + 384u));
            asm volatile("ds_read_b64_tr_b16 %0, %1" : "=v"(tb7) : "v"((kb + 2432u) ^ 16u));
            asm volatile("s_waitcnt lgkmcnt(8)" ::: "memory");
            __builtin_amdgcn_sched_barrier(0);
            union { unsigned u[4]; bh8 v; } A0, A1;
            A0.u[0] = ta0[0]; A0.u[1] = ta0[1]; A0.u[2] = ta1[0]; A0.u[3] = ta1[1];
            A1.u[0] = ta2[0]; A1.u[1] = ta2[1]; A1.u[2] = ta3[0]; A1.u[3] = ta3[1];
            asm volatile("s_waitcnt lgkmcnt(6)" ::: "memory");
            __builtin_amdgcn_sched_barrier(0);
            {
                union { unsigned u[4]; bh8 v; } Bc;
                Bc.u[0] = tb0[0]; Bc.u[1] = tb0[1]; Bc.u[2] = tb1[0]; Bc.u[3] = tb1[1];
                g2[0][0] = MFMA16(A0.v, Bc.v, g2[0][0], 0, 0, 0);
                g2[1][0] = MFMA16(A1.v, Bc.v, g2[1][0], 0, 0, 0);
            }
            asm volatile("s_waitcnt lgkmcnt(4)" ::: "memory");
            __builtin_amdgcn_sched_barrier(0);
            {
                union { unsigned u[4]; bh8 v; } Bc;
                Bc.u[0] = tb2[0]; Bc.u[1] = tb2[1]; Bc.u[2] = tb3[0]; Bc.u[3] = tb3[1];
                g2[0][1] = MFMA16(A0.v, Bc.v, g2[0][1], 0, 0, 0);
                g2[1][1] = MFMA16(A1.v, Bc.v, g2[1][1], 0, 0, 0);
            }
            asm volatile("s_waitcnt lgkmcnt(2)" ::: "memory");
            __builtin_amdgcn_sched_barrier(0);
            {
                union { unsigned u[4]; bh8 v; } Bc;
                Bc.u[0] = tb4[0]; Bc.u[1] = tb4[1]; Bc.u[2] = tb5[0]; Bc.u[3] = tb5[1];
                g2[0][2] = MFMA16(A0.v, Bc.v, g2[0][2], 0, 0, 0);
                g2[1][2] = MFMA16(A1.v, Bc.v, g2[1][2], 0, 0, 0);
            }
            asm volatile("s_waitcnt lgkmcnt(0)" ::: "memory");
            __builtin_amdgcn_sched_barrier(0);
            {
                union { unsigned u[4]; bh8 v; } Bc;
                Bc.u[0] = tb6[0]; Bc.u[1] = tb6[1]; Bc.u[2] = tb7[0]; Bc.u[3] = tb7[1];
                g2[0][3] = MFMA16(A0.v, Bc.v, g2[0][3], 0, 0, 0);
                g2[1][3] = MFMA16(A1.v, Bc.v, g2[1][3], 0, 0, 0);
            }
        }
    }

    // ---- epilogue
    #pragma unroll
    for (int dt = 0; dt < 2; ++dt)
        #pragma unroll
        for (int ct = 0; ct < 4; ++ct)
            #pragma unroll
            for (int r = 0; r < 4; ++r)
                pout[(16 * dt + 4 * l4 + r) * 256 + 64 * w + 16 * ct + l15] = g2[dt][ct][r];

    #pragma unroll
    for (int j = 0; j < 8; ++j) xs[j] += __shfl_xor(xs[j], 32);
    if ((lane >> 5) == 0) {
        #pragma unroll
        for (int j = 0; j < 8; ++j) xred[w][oct * 8 + j] = xs[j];
    }
    __syncthreads();
    {
        float v = xred[0][tid] + xred[1][tid] + xred[2][tid] + xred[3][tid];
        atomicAdd(accsb + 8192 + tid, v);
    }
    if (w < 2) {
        #pragma unroll
        for (int r = 0; r < 4; ++r) {
            float v = kreg[r];
            v += __shfl_xor(v, 1); v += __shfl_xor(v, 2);
            v += __shfl_xor(v, 4); v += __shfl_xor(v, 8);
            if (l15 == 0) atomicAdd(accsb + 8448 + 16 * (w & 1) + 4 * l4 + r, v);
        }
    }
}

// ---------------------------------------------------------------------------
// k2a: reduce 64 per-block KX partials -> acc
// ---------------------------------------------------------------------------
__global__ __launch_bounds__(256)
void k2a_reduce(const float* __restrict__ pbuf, float* __restrict__ acc)
{
    const int b = blockIdx.x, s = blockIdx.y, cs = blockIdx.z;
    const float* __restrict__ p = pbuf + (size_t)(s*BB + b) * 64 * 8192;
    float* __restrict__ a = acc + (size_t)(s*BB + b) * ACC_STRIDE;
    const int d = threadIdx.x >> 3, c = cs * 32 + (threadIdx.x & 7) * 4;
    f4 v = (f4){0.f, 0.f, 0.f, 0.f};
    for (int j = 0; j < 64; ++j)
        v += *(const f4*)(p + (size_t)j * 8192 + d * 256 + c);
    *(f4*)(a + d * 256 + c) = v;
}

// ---------------------------------------------------------------------------
// k2: finalize per (b,s): mat = KX @ Wv^T + ksum0 (x) bv ; vsum = Wv@xsum + N*bv.
//     Also emits matT bf16 [b][c][64] (k = s*32+d) for k3's MFMA A-frags.
// ---------------------------------------------------------------------------
__global__ __launch_bounds__(256, 2)
void k2_finalize(const float* __restrict__ Wv, const float* __restrict__ bv,
                 const float* __restrict__ Wvy, const float* __restrict__ bvy,
                 const float* __restrict__ acc, float* __restrict__ fin,
                 unsigned short* __restrict__ matT)
{
    const int b = blockIdx.x, s = blockIdx.y;
    const float* __restrict__ Wv_ = s ? Wvy : Wv;
    const float* __restrict__ bv_ = s ? bvy : bv;
    const float* __restrict__ a = acc + (size_t)(s*BB + b) * ACC_STRIDE;
    float* __restrict__ f = fin + (size_t)(s*BB + b) * FIN_STRIDE;
    unsigned short* __restrict__ mt = matT + (size_t)b * 16384;

    __shared__ float KXt[256][36];
    __shared__ float xsh[256];
    __shared__ float ks0[32];

    const int tid = threadIdx.x;
    for (int d = 0; d < 32; ++d) KXt[tid][d] = a[d*256 + tid];
    xsh[tid] = a[8192 + tid];
    if (tid < 32) { float v = a[8448 + tid]; ks0[tid] = v; f[8448 + tid] = v + EPSF; }
    __syncthreads();

    const int dh = tid >> 7;
    const int c0 = (tid & 127) * 2;
    float macc[16][2];
    #pragma unroll
    for (int i = 0; i < 16; ++i) { macc[i][0]=0.f; macc[i][1]=0.f; }
    float v0 = 0.f, v1 = 0.f;

    for (int k4 = 0; k4 < 256; k4 += 4) {
        float4 wa = *(const float4*)(Wv_ + (size_t)c0*256 + k4);
        float4 wb = *(const float4*)(Wv_ + (size_t)(c0+1)*256 + k4);
        float4 xv = *(const float4*)&xsh[k4];
        v0 += wa.x*xv.x + wa.y*xv.y + wa.z*xv.z + wa.w*xv.w;
        v1 += wb.x*xv.x + wb.y*xv.y + wb.z*xv.z + wb.w*xv.w;
        #pragma unroll
        for (int u = 0; u < 4; ++u) {
            float wau = (u==0)?wa.x:(u==1)?wa.y:(u==2)?wa.z:wa.w;
            float wbu = (u==0)?wb.x:(u==1)?wb.y:(u==2)?wb.z:wb.w;
            #pragma unroll
            for (int i4 = 0; i4 < 16; i4 += 4) {
                float4 kxv = *(const float4*)&KXt[k4+u][dh*16 + i4];
                macc[i4+0][0] += kxv.x*wau; macc[i4+0][1] += kxv.x*wbu;
                macc[i4+1][0] += kxv.y*wau; macc[i4+1][1] += kxv.y*wbu;
                macc[i4+2][0] += kxv.z*wau; macc[i4+2][1] += kxv.z*wbu;
                macc[i4+3][0] += kxv.w*wau; macc[i4+3][1] += kxv.w*wbu;
            }
        }
    }
    float bvc0 = bv_[c0], bvc1 = bv_[c0+1];
    if (dh == 0) {
        f[8192 + c0]     = v0 + (float)NN * bvc0;
        f[8192 + c0 + 1] = v1 + (float)NN * bvc1;
    }
    union { unsigned short h[16]; uint4 q[2]; } r0u, r1u;
    #pragma unroll
    for (int i = 0; i < 16; ++i) {
        int d = dh*16 + i;
        float m0v = macc[i][0] + ks0[d]*bvc0;
        float m1v = macc[i][1] + ks0[d]*bvc1;
        f[d*256 + c0]     = m0v;
        f[d*256 + c0 + 1] = m1v;
        r0u.h[i] = (unsigned short)bfp(m0v);
        r1u.h[i] = (unsigned short)bfp(m1v);
    }
    const int kk = s * 32 + dh * 16;
    *(uint4*)(mt + (size_t)c0 * 64 + kk)           = r0u.q[0];
    *(uint4*)(mt + (size_t)c0 * 64 + kk + 8)       = r0u.q[1];
    *(uint4*)(mt + (size_t)(c0+1) * 64 + kk)       = r1u.q[0];
    *(uint4*)(mt + (size_t)(c0+1) * 64 + kk + 8)   = r1u.q[1];
}

// ---------------------------------------------------------------------------
// k3: MFMA output kernel. Per block: batch b, 32 positions, both streams.
//   Msb[c][k] bf16 (XOR-swizzled) staged from matT by coalesced uint4 copy.
//   Atb[r][k] bf16 (r=64: 32 x-rows + 32 y-rows; k=64), XOR-swizzled.
//   D[c][r] = sum_k Msb[c][k]*Atb[r][k]; epilogue adds sv[r]*vs[str][c].
// ---------------------------------------------------------------------------
__global__ __launch_bounds__(256, 3)
void k3_output(const unsigned short* __restrict__ qbuf16, const float* __restrict__ fin,
               const unsigned short* __restrict__ matT,
               const float* __restrict__ g_gamma, const float* __restrict__ g_gammay,
               const float* __restrict__ g_gammacx, const float* __restrict__ g_gammacy,
               const float* __restrict__ g_wx1, const float* __restrict__ g_wx2,
               const float* __restrict__ g_wy1, const float* __restrict__ g_wy2,
               float* __restrict__ out)
{
    const int b = blockIdx.y;
    const int p0 = blockIdx.x * 32;
    const float* __restrict__ fx_ = fin + (size_t)(0*BB + b) * FIN_STRIDE;
    const float* __restrict__ fy_ = fin + (size_t)(1*BB + b) * FIN_STRIDE;
    const unsigned short* __restrict__ mb = matT + (size_t)b * 16384;

    __shared__ unsigned short Msb[256 * 64];  // 32 KB
    __shared__ unsigned short Atb[64 * 64];   // 8 KB
    __shared__ float vs[2][256];
    __shared__ float sv[64];
    __shared__ float ksl[2][32];

    const int tid = threadIdx.x;
    if (tid < 64) ksl[tid >> 5][tid & 31] = ((tid < 32) ? fx_ : fy_)[8448 + (tid & 31)];
    vs[0][tid] = fx_[8192 + tid];
    vs[1][tid] = fy_[8192 + tid];

    // stage matT -> Msb (swizzled), fully coalesced 16B copies
    #pragma unroll
    for (int i = 0; i < 8; ++i) {
        int c = (tid >> 3) + i * 32;
        int g8 = tid & 7;
        uint4 v = *(const uint4*)(mb + (size_t)c * 64 + g8 * 8);
        unsigned off = (unsigned)(c * 128 + g8 * 16) ^ (unsigned)((c & 7) << 4);
        *(uint4*)((char*)Msb + off) = v;
    }
    __syncthreads();   // ksl ready for coef phase

    // coef + Atb rows (tid < 64: str=tid>>5, position p0+(tid&31))
    if (tid < 64) {
        const int str = tid >> 5;
        const int p = p0 + (tid & 31);
        const uint4* __restrict__ qp = (const uint4*)(qbuf16 + ((size_t)(str*BB + b) * NN + p) * DD);
        float q[32];
        float ss = 0.f;
        #pragma unroll
        for (int m = 0; m < 4; ++m) {
            uint4 u = qp[m];
            unsigned uu[4] = {u.x, u.y, u.z, u.w};
            #pragma unroll
            for (int j = 0; j < 4; ++j) {
                float lo = bf2f(uu[j] & 0xFFFFu), hi = bf2f(uu[j] >> 16);
                q[m*8 + 2*j] = lo; q[m*8 + 2*j + 1] = hi;
                ss += lo*lo + hi*hi;
            }
        }
        float qn = rsqrtf(ss);
        float dK = 0.f, dKy = 0.f;
        #pragma unroll
        for (int d = 0; d < 32; ++d) { dK += q[d]*ksl[0][d]; dKy += q[d]*ksl[1][d]; }
        dK *= qn; dKy *= qn;
        float clo, chi, svr;
        if (str == 0) {
            float t1 = 1.f / ((float)NN + dK);
            float t2 = 1.f / ((float)NN + dKy);
            float a1c = g_gamma[0]   * g_wx1[0] * t1;
            float a2c = g_gammacx[0] * g_wx2[0] * t2;
            clo = a1c * qn; chi = a2c * qn; svr = a1c + a2c;
        } else {
            float ty1 = 1.f / ((float)NN + dKy);
            float ty2 = 1.f / ((float)NN + dK);
            float b1c = g_gammay[0]  * g_wy1[0] * ty1;
            float b2c = g_gammacy[0] * g_wy2[0] * ty2;
            clo = b2c * qn; chi = b1c * qn; svr = b1c + b2c;
        }
        sv[tid] = svr;
        #pragma unroll
        for (int g = 0; g < 8; ++g) {
            float m0 = (g < 4) ? clo : chi;
            const float* qq = q + (g & 3) * 8;
            uint4 pk;
            pk.x = bfp(m0*qq[0]) | (bfp(m0*qq[1]) << 16);
            pk.y = bfp(m0*qq[2]) | (bfp(m0*qq[3]) << 16);
            pk.z = bfp(m0*qq[4]) | (bfp(m0*qq[5]) << 16);
            pk.w = bfp(m0*qq[6]) | (bfp(m0*qq[7]) << 16);
            unsigned off = (unsigned)(tid * 128 + g * 16) ^ (unsigned)((tid & 7) << 4);
            *(uint4*)((char*)Atb + off) = pk;
        }
    }
    __syncthreads();   // Msb + Atb + sv ready

    // ---- MFMA: wave w -> r-tile w (r = w*16+l15); 16 ctiles x 2 ksteps
    const int w = tid >> 6, lane = tid & 63;
    const int l15 = lane & 15, l4 = lane >> 4;
    const int r = w * 16 + l15;
    f4 accv[16];
    #pragma unroll
    for (int ct = 0; ct < 16; ++ct) accv[ct] = (f4){0.f, 0.f, 0.f, 0.f};

    #pragma unroll
    for (int kstep = 0; kstep < 2; ++kstep) {
        unsigned boff = (unsigned)(r * 128 + kstep * 64 + l4 * 16) ^ (unsigned)((r & 7) << 4);
        bh8 bfr = *(const bh8*)((const char*)Atb + boff);
        #pragma unroll
        for (int ct = 0; ct < 16; ++ct) {
            int c = ct * 16 + l15;
            unsigned aoff = (unsigned)(c * 128 + kstep * 64 + l4 * 16) ^ (unsigned)((c & 7) << 4);
            bh8 afr = *(const bh8*)((const char*)Msb + aoff);
            accv[ct] = MFMA16(afr, bfr, accv[ct], 0, 0, 0);
        }
    }

    // ---- epilogue: add sv[r]*vs and store float4 (lane holds 4 consecutive c)
    const int str = w >> 1;
    const int prow = (w & 1) * 16 + l15;
    float* __restrict__ op = out + (size_t)str * BB * NN * CC + ((size_t)b * NN + p0 + prow) * CC;
    const float svr = sv[r];
    #pragma unroll
    for (int ct = 0; ct < 16; ++ct) {
        int c0 = ct * 16 + 4 * l4;
        float4 vsv = *(const float4*)&vs[str][c0];
        float4 o = make_float4(accv[ct][0] + svr*vsv.x, accv[ct][1] + svr*vsv.y,
                               accv[ct][2] + svr*vsv.z, accv[ct][3] + svr*vsv.w);
        *(float4*)(op + c0) = o;
    }
}

extern "C" void kernel_launch(void* const* d_in, const int* in_sizes, int n_in,
                              void* d_out, int out_size, void* d_ws, size_t ws_size,
                              hipStream_t stream)
{
    (void)in_sizes; (void)n_in; (void)out_size; (void)ws_size;
    const float* x   = (const float*)d_in[0];
    const float* y   = (const float*)d_in[1];
    const float* Wq  = (const float*)d_in[2];
    const float* bq  = (const float*)d_in[3];
    const float* Wk  = (const float*)d_in[4];
    const float* bk  = (const float*)d_in[5];
    const float* Wv  = (const float*)d_in[6];
    const float* bv  = (const float*)d_in[7];
    const float* Wqy = (const float*)d_in[8];
    const float* bqy = (const float*)d_in[9];
    const float* Wky = (const float*)d_in[10];
    const float* bky = (const float*)d_in[11];
    const float* Wvy = (const float*)d_in[12];
    const float* bvy = (const float*)d_in[13];

    float* ws   = (float*)d_ws;
    unsigned short* qbuf16 = (unsigned short*)ws;
    float* acc  = ws + ACC_OFF;
    float* fin  = ws + FIN_OFF;
    unsigned short* wbf  = (unsigned short*)(ws + WBF_OFF);
    unsigned short* matT = (unsigned short*)(ws + MATT_OFF);
    float* pbuf = (float*)d_out;    // scratch: fully consumed by k2a before k3 overwrites

    k0_cvt<<<128, 256, 0, stream>>>(Wk, Wq, Wky, Wqy, wbf);
    hipMemsetAsync(acc, 0, ACC_FLOATS * sizeof(float), stream);

    k1_proj<<<dim3(64, BB, 2), 256, 0, stream>>>(x, y, wbf, bk, bq, bky, bqy, qbuf16, acc, pbuf);
    k2a_reduce<<<dim3(BB, 2, 8), 256, 0, stream>>>(pbuf, acc);
    k2_finalize<<<dim3(BB, 2), 256, 0, stream>>>(Wv, bv, Wvy, bvy, acc, fin, matT);
    k3_output<<<dim3(NN/32, BB), 256, 0, stream>>>(qbuf16, fin, matT,
        (const float*)d_in[14], (const float*)d_in[15], (const float*)d_in[16], (const float*)d_in[17],
        (const float*)d_in[18], (const float*)d_in[19], (const float*)d_in[20], (const float*)d_in[21],
        (float*)d_out);
}

// Round 9
// 198.206 us; speedup vs baseline: 2.0614x; 1.7544x over previous
//
#include <hip/hip_runtime.h>

#define BB 8
#define NN 16384
#define CC 256
#define DD 32
#define EPSF 1e-6f

// ws layout (float units)
#define QBUF_FLOATS (2ull*BB*NN*DD)            // reserved (qbuf is bf16, uses half)
#define ACC_STRIDE 8480                         // per (s,b): KX[32][256], xsum[256], ksum0[32]
#define ACC_OFF QBUF_FLOATS
#define ACC_FLOATS (16*ACC_STRIDE)
#define FIN_OFF (ACC_OFF + ACC_FLOATS)
#define FIN_STRIDE 8480
#define WBF_OFF (FIN_OFF + 16*FIN_STRIDE)       // 32768 ushort = 16384 floats
#define MATT_OFF (WBF_OFF + 16384)              // 131072 ushort (bf16 matT [b][c][64])

typedef __attribute__((ext_vector_type(8))) short bh8;
typedef __attribute__((ext_vector_type(4))) float f4;
typedef __attribute__((ext_vector_type(2))) unsigned int u32x2;

__device__ __forceinline__ unsigned int bfp(float f) {
    unsigned int u = __float_as_uint(f);
    return (u + 0x7FFFu + ((u >> 16) & 1u)) >> 16;   // RNE fp32->bf16 bits
}
__device__ __forceinline__ float bf2f(unsigned int h) {
    return __uint_as_float(h << 16);
}

#define MFMA16 __builtin_amdgcn_mfma_f32_16x16x32_bf16

// lgkm-only barrier: LDS visibility without draining vmcnt (keeps global loads in flight)
#define LBAR() do { \
    asm volatile("s_waitcnt lgkmcnt(0)" ::: "memory"); \
    __builtin_amdgcn_s_barrier(); \
    __builtin_amdgcn_sched_barrier(0); \
} while (0)

// ---------------------------------------------------------------------------
// k0: convert the 4 projection weight matrices to bf16 once.
// ---------------------------------------------------------------------------
__global__ __launch_bounds__(256)
void k0_cvt(const float* __restrict__ Wk, const float* __restrict__ Wq,
            const float* __restrict__ Wky, const float* __restrict__ Wqy,
            unsigned short* __restrict__ wbf)
{
    int i = blockIdx.x * 256 + threadIdx.x;
    const float* p = (i < 8192) ? Wk : (i < 16384) ? Wq : (i < 24576) ? Wky : Wqy;
    wbf[i] = (unsigned short)bfp(p[i & 8191]);
}

// ---------------------------------------------------------------------------
// k1: 32-row chunks x8, double-buffered LDS, TWO-DEEP register prefetch with
//     NAMED register sets (A* even chunks / C* odd chunks) and an explicit
//     two-phase loop body -> every register index is compile-time (rule #20).
//     launch_bounds(256,2): VGPR cap 256, no spill possible at ~160 use.
//     GEMM1: D'[d][p] = W.X^T + bias (W frags in VGPRs).
//     GEMM2: KX[d][c] += K^T.X via ds_read_b64_tr_b16, counted lgkm pipeline.
// ---------------------------------------------------------------------------
__global__ __launch_bounds__(256, 2)
void k1_proj(const float* __restrict__ x, const float* __restrict__ y,
             const unsigned short* __restrict__ wbf,
             const float* __restrict__ bk, const float* __restrict__ bq,
             const float* __restrict__ bky, const float* __restrict__ bqy,
             unsigned short* __restrict__ qbuf16, float* __restrict__ acc,
             float* __restrict__ pbuf)
{
    const int b = blockIdx.y, s = blockIdx.z;
    const float* __restrict__ src = (s ? y : x) + (size_t)b * NN * CC;
    unsigned short* __restrict__ qb = qbuf16 + (size_t)(s*BB + b) * NN * DD;
    float* __restrict__ accsb = acc + (size_t)(s*BB + b) * ACC_STRIDE;
    float* __restrict__ pout = pbuf + ((size_t)((s*BB + b) * 64 + blockIdx.x)) * 8192;

    __shared__ unsigned short Xsub[2][8192];   // 2 x 16 KB subtiled bf16 (32 rows each)
    __shared__ unsigned short Ksb[1024];       // 2 KB [p][d]-subtiled bf16 K (32 p)
    __shared__ float red[4][32];               // norm partials
    __shared__ float xred[4][256];             // xsum cross-wave

    const int tid = threadIdx.x;
    const int w = tid >> 6, lane = tid & 63;
    const int l15 = lane & 15, l4 = lane >> 4;
    const int oct = lane & 31;
    const int rower = tid >> 5;                // 0..7

    // weight frags: matrix (s*2 + (w>>1)), rows 16*(w&1)+l15
    const unsigned short* __restrict__ wm =
        wbf + (size_t)(s * 2 + (w >> 1)) * 8192 + (size_t)(16 * (w & 1) + l15) * 256 + 8 * l4;
    bh8 wf[8];
    #pragma unroll
    for (int ks = 0; ks < 8; ++ks) wf[ks] = *(const bh8*)(wm + 32 * ks);
    const float* __restrict__ bp = (w < 2) ? (s ? bky : bk) : (s ? bqy : bq);
    const f4 bias4 = *(const f4*)(bp + 16 * (w & 1) + 4 * l4);

    // staging LDS byte (row r = it*8 + rower, cols oct*8..+7), it stride 4096
    const int hv = (rower >> 2) & 1;
    const int wbyte0 = (hv * 2048 + (oct >> 1) * 128 + (rower & 3) * 32 + (oct & 1) * 16) ^ (hv << 4);
    // GEMM1 B-frag: p = 16*pt + l15, c = 32ks+8l4
    int ab[2];
    #pragma unroll
    for (int pt = 0; pt < 2; ++pt) {
        int aq = 4 * pt + (l15 >> 2);
        ab[pt] = ((aq * 2048 + (l15 & 3) * 32 + (l4 & 1) * 16) ^ ((aq & 1) << 4)) + (l4 >> 1) * 128;
    }
    const unsigned xb0 = (unsigned)(uintptr_t)&Xsub[0][0];
    const unsigned kbase = (unsigned)(uintptr_t)&Ksb[0];
    const unsigned btr_rel = (unsigned)(2 * l4 * 2048 + 4 * w * 128 + l15 * 8);
    const unsigned atr = kbase + (unsigned)(2 * l4 * 256 + l15 * 8);

    f4 g2[2][4];
    #pragma unroll
    for (int dt = 0; dt < 2; ++dt)
        #pragma unroll
        for (int ct = 0; ct < 4; ++ct) g2[dt][ct] = (f4){0.f, 0.f, 0.f, 0.f};
    float xs[8];
    #pragma unroll
    for (int j = 0; j < 8; ++j) xs[j] = 0.f;
    float kreg[4] = {0.f, 0.f, 0.f, 0.f};

    const float* __restrict__ gbase = src + (size_t)(blockIdx.x * 256 + rower) * CC + oct * 8;

    // chunk compute: GEMM1 + norms + K/Q emit + GEMM2 (no staged regs touched)
    auto do_chunk = [&](char* xcur, unsigned kb, int ch) {
        LBAR();   // S1: Xsub[buf] visible; global loads stay in flight
        f4 a1_0 = bias4, a1_1 = bias4;
        #pragma unroll
        for (int ks = 0; ks < 8; ++ks) {
            bh8 xv0 = *(const bh8*)(xcur + ab[0] + ks * 256);
            bh8 xv1 = *(const bh8*)(xcur + ab[1] + ks * 256);
            a1_0 = MFMA16(wf[ks], xv0, a1_0, 0, 0, 0);
            a1_1 = MFMA16(wf[ks], xv1, a1_1, 0, 0, 0);
        }
        // norm partials
        {
            float s0 = a1_0[0]*a1_0[0] + a1_0[1]*a1_0[1] + a1_0[2]*a1_0[2] + a1_0[3]*a1_0[3];
            float s1 = a1_1[0]*a1_1[0] + a1_1[1]*a1_1[1] + a1_1[2]*a1_1[2] + a1_1[3]*a1_1[3];
            s0 += __shfl_xor(s0, 16); s0 += __shfl_xor(s0, 32);
            s1 += __shfl_xor(s1, 16); s1 += __shfl_xor(s1, 32);
            if (l4 == 0) { red[w][l15] = s0; red[w][16 + l15] = s1; }
        }
        LBAR();   // S2: red visible
        if (w < 2) {
            {
                int p = l15;
                float n = rsqrtf(red[0][p] + red[1][p]);
                float k0 = a1_0[0]*n, k1 = a1_0[1]*n, k2 = a1_0[2]*n, k3 = a1_0[3]*n;
                kreg[0] += k0; kreg[1] += k1; kreg[2] += k2; kreg[3] += k3;
                *(uint2*)((char*)Ksb + (p >> 2) * 256 + (w & 1) * 128 + (p & 3) * 32 + 8 * l4)
                    = make_uint2(bfp(k0) | (bfp(k1) << 16), bfp(k2) | (bfp(k3) << 16));
            }
            {
                int p = 16 + l15;
                float n = rsqrtf(red[0][p] + red[1][p]);
                float k0 = a1_1[0]*n, k1 = a1_1[1]*n, k2 = a1_1[2]*n, k3 = a1_1[3]*n;
                kreg[0] += k0; kreg[1] += k1; kreg[2] += k2; kreg[3] += k3;
                *(uint2*)((char*)Ksb + (p >> 2) * 256 + (w & 1) * 128 + (p & 3) * 32 + 8 * l4)
                    = make_uint2(bfp(k0) | (bfp(k1) << 16), bfp(k2) | (bfp(k3) << 16));
            }
        } else {
            {
                int p = l15;
                float n = rsqrtf(red[2][p] + red[3][p]);
                *(uint2*)(qb + (size_t)(blockIdx.x*256 + ch*32 + p) * DD + 16 * (w & 1) + 4 * l4)
                    = make_uint2(bfp(a1_0[0]*n) | (bfp(a1_0[1]*n) << 16),
                                 bfp(a1_0[2]*n) | (bfp(a1_0[3]*n) << 16));
            }
            {
                int p = 16 + l15;
                float n = rsqrtf(red[2][p] + red[3][p]);
                *(uint2*)(qb + (size_t)(blockIdx.x*256 + ch*32 + p) * DD + 16 * (w & 1) + 4 * l4)
                    = make_uint2(bfp(a1_1[0]*n) | (bfp(a1_1[1]*n) << 16),
                                 bfp(a1_1[2]*n) | (bfp(a1_1[3]*n) << 16));
            }
        }
        LBAR();   // S3: Ksb visible
        // GEMM2 via tr-reads, counted lgkm pipeline
        u32x2 ta0, ta1, ta2, ta3, tb0, tb1, tb2, tb3, tb4, tb5, tb6, tb7;
        asm volatile("ds_read_b64_tr_b16 %0, %1" : "=v"(ta0) : "v"(atr));
        asm volatile("ds_read_b64_tr_b16 %0, %1" : "=v"(ta1) : "v"(atr + 256u));
        asm volatile("ds_read_b64_tr_b16 %0, %1" : "=v"(ta2) : "v"(atr + 128u));
        asm volatile("ds_read_b64_tr_b16 %0, %1" : "=v"(ta3) : "v"(atr + 384u));
        asm volatile("ds_read_b64_tr_b16 %0, %1" : "=v"(tb0) : "v"(kb));
        asm volatile("ds_read_b64_tr_b16 %0, %1" : "=v"(tb1) : "v"((kb + 2048u) ^ 16u));
        asm volatile("ds_read_b64_tr_b16 %0, %1" : "=v"(tb2) : "v"(kb + 128u));
        asm volatile("ds_read_b64_tr_b16 %0, %1" : "=v"(tb3) : "v"((kb + 2176u) ^ 16u));
        asm volatile("ds_read_b64_tr_b16 %0, %1" : "=v"(tb4) : "v"(kb + 256u));
        asm volatile("ds_read_b64_tr_b16 %0, %1" : "=v"(tb5) : "v"((kb + 2304u) ^ 16u));
        asm volatile("ds_read_b64_tr_b16 %0, %1" : "=v"(tb6) : "v"(kb + 384u));
        asm volatile("ds_read_b64_tr_b16 %0, %1" : "=v"(tb7) : "v"((kb + 2432u) ^ 16u));
        asm volatile("s_waitcnt lgkmcnt(8)" ::: "memory");
        __builtin_amdgcn_sched_barrier(0);
        union { unsigned u[4]; bh8 v; } A0, A1;
        A0.u[0] = ta0[0]; A0.u[1] = ta0[1]; A0.u[2] = ta1[0]; A0.u[3] = ta1[1];
        A1.u[0] = ta2[0]; A1.u[1] = ta2[1]; A1.u[2] = ta3[0]; A1.u[3] = ta3[1];
        asm volatile("s_waitcnt lgkmcnt(6)" ::: "memory");
        __builtin_amdgcn_sched_barrier(0);
        {
            union { unsigned u[4]; bh8 v; } Bc;
            Bc.u[0] = tb0[0]; Bc.u[1] = tb0[1]; Bc.u[2] = tb1[0]; Bc.u[3] = tb1[1];
            g2[0][0] = MFMA16(A0.v, Bc.v, g2[0][0], 0, 0, 0);
            g2[1][0] = MFMA16(A1.v, Bc.v, g2[1][0], 0, 0, 0);
        }
        asm volatile("s_waitcnt lgkmcnt(4)" ::: "memory");
        __builtin_amdgcn_sched_barrier(0);
        {
            union { unsigned u[4]; bh8 v; } Bc;
            Bc.u[0] = tb2[0]; Bc.u[1] = tb2[1]; Bc.u[2] = tb3[0]; Bc.u[3] = tb3[1];
            g2[0][1] = MFMA16(A0.v, Bc.v, g2[0][1], 0, 0, 0);
            g2[1][1] = MFMA16(A1.v, Bc.v, g2[1][1], 0, 0, 0);
        }
        asm volatile("s_waitcnt lgkmcnt(2)" ::: "memory");
        __builtin_amdgcn_sched_barrier(0);
        {
            union { unsigned u[4]; bh8 v; } Bc;
            Bc.u[0] = tb4[0]; Bc.u[1] = tb4[1]; Bc.u[2] = tb5[0]; Bc.u[3] = tb5[1];
            g2[0][2] = MFMA16(A0.v, Bc.v, g2[0][2], 0, 0, 0);
            g2[1][2] = MFMA16(A1.v, Bc.v, g2[1][2], 0, 0, 0);
        }
        asm volatile("s_waitcnt lgkmcnt(0)" ::: "memory");
        __builtin_amdgcn_sched_barrier(0);
        {
            union { unsigned u[4]; bh8 v; } Bc;
            Bc.u[0] = tb6[0]; Bc.u[1] = tb6[1]; Bc.u[2] = tb7[0]; Bc.u[3] = tb7[1];
            g2[0][3] = MFMA16(A0.v, Bc.v, g2[0][3], 0, 0, 0);
            g2[1][3] = MFMA16(A1.v, Bc.v, g2[1][3], 0, 0, 0);
        }
    };

// named-register staging helpers (all indices compile-time)
#define LOADSET(R0,R1,R2,R3,R4,R5,R6,R7, CHIX) do { \
    const float* gn_ = gbase + (size_t)((CHIX) * 32) * CC; \
    R0 = *(const float4*)(gn_);              R1 = *(const float4*)(gn_ + 4); \
    R2 = *(const float4*)(gn_ +  8*CC);      R3 = *(const float4*)(gn_ +  8*CC + 4); \
    R4 = *(const float4*)(gn_ + 16*CC);      R5 = *(const float4*)(gn_ + 16*CC + 4); \
    R6 = *(const float4*)(gn_ + 24*CC);      R7 = *(const float4*)(gn_ + 24*CC + 4); \
} while (0)

#define PACK1(Av, Bv, XCUR, ITOFF) do { \
    xs[0] += Av.x; xs[1] += Av.y; xs[2] += Av.z; xs[3] += Av.w; \
    xs[4] += Bv.x; xs[5] += Bv.y; xs[6] += Bv.z; xs[7] += Bv.w; \
    uint4 pk_; \
    pk_.x = bfp(Av.x) | (bfp(Av.y) << 16); \
    pk_.y = bfp(Av.z) | (bfp(Av.w) << 16); \
    pk_.z = bfp(Bv.x) | (bfp(Bv.y) << 16); \
    pk_.w = bfp(Bv.z) | (bfp(Bv.w) << 16); \
    *(uint4*)((XCUR) + wbyte0 + (ITOFF)) = pk_; \
} while (0)

#define CONSUME(R0,R1,R2,R3,R4,R5,R6,R7, XCUR) do { \
    PACK1(R0, R1, XCUR, 0); \
    PACK1(R2, R3, XCUR, 4096); \
    PACK1(R4, R5, XCUR, 8192); \
    PACK1(R6, R7, XCUR, 12288); \
} while (0)

    float4 A0,A1,A2,A3,A4,A5,A6,A7;   // even-chunk stage set
    float4 C0,C1,C2,C3,C4,C5,C6,C7;   // odd-chunk stage set

    // prologue: chunks 0 and 1 in flight (2-deep)
    LOADSET(A0,A1,A2,A3,A4,A5,A6,A7, 0);
    LOADSET(C0,C1,C2,C3,C4,C5,C6,C7, 1);

    char* xbuf0 = (char*)&Xsub[0][0];
    char* xbuf1 = (char*)&Xsub[1][0];

    for (int it2 = 0; it2 < 4; ++it2) {
        const int che = 2 * it2, cho = che + 1;
        // phase even: buffer 0, set A
        CONSUME(A0,A1,A2,A3,A4,A5,A6,A7, xbuf0);
        if (it2 < 3) LOADSET(A0,A1,A2,A3,A4,A5,A6,A7, che + 2);
        do_chunk(xbuf0, xb0 + btr_rel, che);
        // phase odd: buffer 1, set C
        CONSUME(C0,C1,C2,C3,C4,C5,C6,C7, xbuf1);
        if (it2 < 3) LOADSET(C0,C1,C2,C3,C4,C5,C6,C7, cho + 2);
        do_chunk(xbuf1, xb0 + 16384u + btr_rel, cho);
    }
#undef LOADSET
#undef PACK1
#undef CONSUME

    // ---- epilogue
    #pragma unroll
    for (int dt = 0; dt < 2; ++dt)
        #pragma unroll
        for (int ct = 0; ct < 4; ++ct)
            #pragma unroll
            for (int r = 0; r < 4; ++r)
                pout[(16 * dt + 4 * l4 + r) * 256 + 64 * w + 16 * ct + l15] = g2[dt][ct][r];

    #pragma unroll
    for (int j = 0; j < 8; ++j) xs[j] += __shfl_xor(xs[j], 32);
    if ((lane >> 5) == 0) {
        #pragma unroll
        for (int j = 0; j < 8; ++j) xred[w][oct * 8 + j] = xs[j];
    }
    __syncthreads();
    {
        float v = xred[0][tid] + xred[1][tid] + xred[2][tid] + xred[3][tid];
        atomicAdd(accsb + 8192 + tid, v);
    }
    if (w < 2) {
        #pragma unroll
        for (int r = 0; r < 4; ++r) {
            float v = kreg[r];
            v += __shfl_xor(v, 1); v += __shfl_xor(v, 2);
            v += __shfl_xor(v, 4); v += __shfl_xor(v, 8);
            if (l15 == 0) atomicAdd(accsb + 8448 + 16 * (w & 1) + 4 * l4 + r, v);
        }
    }
}

// ---------------------------------------------------------------------------
// k2a: reduce 64 per-block KX partials -> acc
// ---------------------------------------------------------------------------
__global__ __launch_bounds__(256)
void k2a_reduce(const float* __restrict__ pbuf, float* __restrict__ acc)
{
    const int b = blockIdx.x, s = blockIdx.y, cs = blockIdx.z;
    const float* __restrict__ p = pbuf + (size_t)(s*BB + b) * 64 * 8192;
    float* __restrict__ a = acc + (size_t)(s*BB + b) * ACC_STRIDE;
    const int d = threadIdx.x >> 3, c = cs * 32 + (threadIdx.x & 7) * 4;
    f4 v = (f4){0.f, 0.f, 0.f, 0.f};
    for (int j = 0; j < 64; ++j)
        v += *(const f4*)(p + (size_t)j * 8192 + d * 256 + c);
    *(f4*)(a + d * 256 + c) = v;
}

// ---------------------------------------------------------------------------
// k2: finalize per (b,s): mat = KX @ Wv^T + ksum0 (x) bv ; vsum = Wv@xsum + N*bv.
//     Also emits matT bf16 [b][c][64] (k = s*32+d) for k3's MFMA A-frags.
// ---------------------------------------------------------------------------
__global__ __launch_bounds__(256, 2)
void k2_finalize(const float* __restrict__ Wv, const float* __restrict__ bv,
                 const float* __restrict__ Wvy, const float* __restrict__ bvy,
                 const float* __restrict__ acc, float* __restrict__ fin,
                 unsigned short* __restrict__ matT)
{
    const int b = blockIdx.x, s = blockIdx.y;
    const float* __restrict__ Wv_ = s ? Wvy : Wv;
    const float* __restrict__ bv_ = s ? bvy : bv;
    const float* __restrict__ a = acc + (size_t)(s*BB + b) * ACC_STRIDE;
    float* __restrict__ f = fin + (size_t)(s*BB + b) * FIN_STRIDE;
    unsigned short* __restrict__ mt = matT + (size_t)b * 16384;

    __shared__ float KXt[256][36];
    __shared__ float xsh[256];
    __shared__ float ks0[32];

    const int tid = threadIdx.x;
    for (int d = 0; d < 32; ++d) KXt[tid][d] = a[d*256 + tid];
    xsh[tid] = a[8192 + tid];
    if (tid < 32) { float v = a[8448 + tid]; ks0[tid] = v; f[8448 + tid] = v + EPSF; }
    __syncthreads();

    const int dh = tid >> 7;
    const int c0 = (tid & 127) * 2;
    float macc[16][2];
    #pragma unroll
    for (int i = 0; i < 16; ++i) { macc[i][0]=0.f; macc[i][1]=0.f; }
    float v0 = 0.f, v1 = 0.f;

    for (int k4 = 0; k4 < 256; k4 += 4) {
        float4 wa = *(const float4*)(Wv_ + (size_t)c0*256 + k4);
        float4 wb = *(const float4*)(Wv_ + (size_t)(c0+1)*256 + k4);
        float4 xv = *(const float4*)&xsh[k4];
        v0 += wa.x*xv.x + wa.y*xv.y + wa.z*xv.z + wa.w*xv.w;
        v1 += wb.x*xv.x + wb.y*xv.y + wb.z*xv.z + wb.w*xv.w;
        #pragma unroll
        for (int u = 0; u < 4; ++u) {
            float wau = (u==0)?wa.x:(u==1)?wa.y:(u==2)?wa.z:wa.w;
            float wbu = (u==0)?wb.x:(u==1)?wb.y:(u==2)?wb.z:wb.w;
            #pragma unroll
            for (int i4 = 0; i4 < 16; i4 += 4) {
                float4 kxv = *(const float4*)&KXt[k4+u][dh*16 + i4];
                macc[i4+0][0] += kxv.x*wau; macc[i4+0][1] += kxv.x*wbu;
                macc[i4+1][0] += kxv.y*wau; macc[i4+1][1] += kxv.y*wbu;
                macc[i4+2][0] += kxv.z*wau; macc[i4+2][1] += kxv.z*wbu;
                macc[i4+3][0] += kxv.w*wau; macc[i4+3][1] += kxv.w*wbu;
            }
        }
    }
    float bvc0 = bv_[c0], bvc1 = bv_[c0+1];
    if (dh == 0) {
        f[8192 + c0]     = v0 + (float)NN * bvc0;
        f[8192 + c0 + 1] = v1 + (float)NN * bvc1;
    }
    union { unsigned short h[16]; uint4 q[2]; } r0u, r1u;
    #pragma unroll
    for (int i = 0; i < 16; ++i) {
        int d = dh*16 + i;
        float m0v = macc[i][0] + ks0[d]*bvc0;
        float m1v = macc[i][1] + ks0[d]*bvc1;
        f[d*256 + c0]     = m0v;
        f[d*256 + c0 + 1] = m1v;
        r0u.h[i] = (unsigned short)bfp(m0v);
        r1u.h[i] = (unsigned short)bfp(m1v);
    }
    const int kk = s * 32 + dh * 16;
    *(uint4*)(mt + (size_t)c0 * 64 + kk)           = r0u.q[0];
    *(uint4*)(mt + (size_t)c0 * 64 + kk + 8)       = r0u.q[1];
    *(uint4*)(mt + (size_t)(c0+1) * 64 + kk)       = r1u.q[0];
    *(uint4*)(mt + (size_t)(c0+1) * 64 + kk + 8)   = r1u.q[1];
}

// ---------------------------------------------------------------------------
// k3: MFMA output kernel. Per block: batch b, 32 positions, both streams.
//   Msb[c][k] bf16 (XOR-swizzled) staged from matT by coalesced uint4 copy.
//   Atb[r][k] bf16 (r=64: 32 x-rows + 32 y-rows; k=64), XOR-swizzled.
//   D[c][r] = sum_k Msb[c][k]*Atb[r][k]; epilogue adds sv[r]*vs[str][c].
// ---------------------------------------------------------------------------
__global__ __launch_bounds__(256, 3)
void k3_output(const unsigned short* __restrict__ qbuf16, const float* __restrict__ fin,
               const unsigned short* __restrict__ matT,
               const float* __restrict__ g_gamma, const float* __restrict__ g_gammay,
               const float* __restrict__ g_gammacx, const float* __restrict__ g_gammacy,
               const float* __restrict__ g_wx1, const float* __restrict__ g_wx2,
               const float* __restrict__ g_wy1, const float* __restrict__ g_wy2,
               float* __restrict__ out)
{
    const int b = blockIdx.y;
    const int p0 = blockIdx.x * 32;
    const float* __restrict__ fx_ = fin + (size_t)(0*BB + b) * FIN_STRIDE;
    const float* __restrict__ fy_ = fin + (size_t)(1*BB + b) * FIN_STRIDE;
    const unsigned short* __restrict__ mb = matT + (size_t)b * 16384;

    __shared__ unsigned short Msb[256 * 64];  // 32 KB
    __shared__ unsigned short Atb[64 * 64];   // 8 KB
    __shared__ float vs[2][256];
    __shared__ float sv[64];
    __shared__ float ksl[2][32];

    const int tid = threadIdx.x;
    if (tid < 64) ksl[tid >> 5][tid & 31] = ((tid < 32) ? fx_ : fy_)[8448 + (tid & 31)];
    vs[0][tid] = fx_[8192 + tid];
    vs[1][tid] = fy_[8192 + tid];

    // stage matT -> Msb (swizzled), fully coalesced 16B copies
    #pragma unroll
    for (int i = 0; i < 8; ++i) {
        int c = (tid >> 3) + i * 32;
        int g8 = tid & 7;
        uint4 v = *(const uint4*)(mb + (size_t)c * 64 + g8 * 8);
        unsigned off = (unsigned)(c * 128 + g8 * 16) ^ (unsigned)((c & 7) << 4);
        *(uint4*)((char*)Msb + off) = v;
    }
    __syncthreads();   // ksl ready for coef phase

    // coef + Atb rows (tid < 64: str=tid>>5, position p0+(tid&31))
    if (tid < 64) {
        const int str = tid >> 5;
        const int p = p0 + (tid & 31);
        const uint4* __restrict__ qp = (const uint4*)(qbuf16 + ((size_t)(str*BB + b) * NN + p) * DD);
        float q[32];
        float ss = 0.f;
        #pragma unroll
        for (int m = 0; m < 4; ++m) {
            uint4 u = qp[m];
            unsigned uu[4] = {u.x, u.y, u.z, u.w};
            #pragma unroll
            for (int j = 0; j < 4; ++j) {
                float lo = bf2f(uu[j] & 0xFFFFu), hi = bf2f(uu[j] >> 16);
                q[m*8 + 2*j] = lo; q[m*8 + 2*j + 1] = hi;
                ss += lo*lo + hi*hi;
            }
        }
        float qn = rsqrtf(ss);
        float dK = 0.f, dKy = 0.f;
        #pragma unroll
        for (int d = 0; d < 32; ++d) { dK += q[d]*ksl[0][d]; dKy += q[d]*ksl[1][d]; }
        dK *= qn; dKy *= qn;
        float clo, chi, svr;
        if (str == 0) {
            float t1 = 1.f / ((float)NN + dK);
            float t2 = 1.f / ((float)NN + dKy);
            float a1c = g_gamma[0]   * g_wx1[0] * t1;
            float a2c = g_gammacx[0] * g_wx2[0] * t2;
            clo = a1c * qn; chi = a2c * qn; svr = a1c + a2c;
        } else {
            float ty1 = 1.f / ((float)NN + dKy);
            float ty2 = 1.f / ((float)NN + dK);
            float b1c = g_gammay[0]  * g_wy1[0] * ty1;
            float b2c = g_gammacy[0] * g_wy2[0] * ty2;
            clo = b2c * qn; chi = b1c * qn; svr = b1c + b2c;
        }
        sv[tid] = svr;
        #pragma unroll
        for (int g = 0; g < 8; ++g) {
            float m0 = (g < 4) ? clo : chi;
            const float* qq = q + (g & 3) * 8;
            uint4 pk;
            pk.x = bfp(m0*qq[0]) | (bfp(m0*qq[1]) << 16);
            pk.y = bfp(m0*qq[2]) | (bfp(m0*qq[3]) << 16);
            pk.z = bfp(m0*qq[4]) | (bfp(m0*qq[5]) << 16);
            pk.w = bfp(m0*qq[6]) | (bfp(m0*qq[7]) << 16);
            unsigned off = (unsigned)(tid * 128 + g * 16) ^ (unsigned)((tid & 7) << 4);
            *(uint4*)((char*)Atb + off) = pk;
        }
    }
    __syncthreads();   // Msb + Atb + sv ready

    // ---- MFMA: wave w -> r-tile w (r = w*16+l15); 16 ctiles x 2 ksteps
    const int w = tid >> 6, lane = tid & 63;
    const int l15 = lane & 15, l4 = lane >> 4;
    const int r = w * 16 + l15;
    f4 accv[16];
    #pragma unroll
    for (int ct = 0; ct < 16; ++ct) accv[ct] = (f4){0.f, 0.f, 0.f, 0.f};

    #pragma unroll
    for (int kstep = 0; kstep < 2; ++kstep) {
        unsigned boff = (unsigned)(r * 128 + kstep * 64 + l4 * 16) ^ (unsigned)((r & 7) << 4);
        bh8 bfr = *(const bh8*)((const char*)Atb + boff);
        #pragma unroll
        for (int ct = 0; ct < 16; ++ct) {
            int c = ct * 16 + l15;
            unsigned aoff = (unsigned)(c * 128 + kstep * 64 + l4 * 16) ^ (unsigned)((c & 7) << 4);
            bh8 afr = *(const bh8*)((const char*)Msb + aoff);
            accv[ct] = MFMA16(afr, bfr, accv[ct], 0, 0, 0);
        }
    }

    // ---- epilogue: add sv[r]*vs and store float4 (lane holds 4 consecutive c)
    const int str = w >> 1;
    const int prow = (w & 1) * 16 + l15;
    float* __restrict__ op = out + (size_t)str * BB * NN * CC + ((size_t)b * NN + p0 + prow) * CC;
    const float svr = sv[r];
    #pragma unroll
    for (int ct = 0; ct < 16; ++ct) {
        int c0 = ct * 16 + 4 * l4;
        float4 vsv = *(const float4*)&vs[str][c0];
        float4 o = make_float4(accv[ct][0] + svr*vsv.x, accv[ct][1] + svr*vsv.y,
                               accv[ct][2] + svr*vsv.z, accv[ct][3] + svr*vsv.w);
        *(float4*)(op + c0) = o;
    }
}

extern "C" void kernel_launch(void* const* d_in, const int* in_sizes, int n_in,
                              void* d_out, int out_size, void* d_ws, size_t ws_size,
                              hipStream_t stream)
{
    (void)in_sizes; (void)n_in; (void)out_size; (void)ws_size;
    const float* x   = (const float*)d_in[0];
    const float* y   = (const float*)d_in[1];
    const float* Wq  = (const float*)d_in[2];
    const float* bq  = (const float*)d_in[3];
    const float* Wk  = (const float*)d_in[4];
    const float* bk  = (const float*)d_in[5];
    const float* Wv  = (const float*)d_in[6];
    const float* bv  = (const float*)d_in[7];
    const float* Wqy = (const float*)d_in[8];
    const float* bqy = (const float*)d_in[9];
    const float* Wky = (const float*)d_in[10];
    const float* bky = (const float*)d_in[11];
    const float* Wvy = (const float*)d_in[12];
    const float* bvy = (const float*)d_in[13];

    float* ws   = (float*)d_ws;
    unsigned short* qbuf16 = (unsigned short*)ws;
    float* acc  = ws + ACC_OFF;
    float* fin  = ws + FIN_OFF;
    unsigned short* wbf  = (unsigned short*)(ws + WBF_OFF);
    unsigned short* matT = (unsigned short*)(ws + MATT_OFF);
    float* pbuf = (float*)d_out;    // scratch: fully consumed by k2a before k3 overwrites

    k0_cvt<<<128, 256, 0, stream>>>(Wk, Wq, Wky, Wqy, wbf);
    hipMemsetAsync(acc, 0, ACC_FLOATS * sizeof(float), stream);

    k1_proj<<<dim3(64, BB, 2), 256, 0, stream>>>(x, y, wbf, bk, bq, bky, bqy, qbuf16, acc, pbuf);
    k2a_reduce<<<dim3(BB, 2, 8), 256, 0, stream>>>(pbuf, acc);
    k2_finalize<<<dim3(BB, 2), 256, 0, stream>>>(Wv, bv, Wvy, bvy, acc, fin, matT);
    k3_output<<<dim3(NN/32, BB), 256, 0, stream>>>(qbuf16, fin, matT,
        (const float*)d_in[14], (const float*)d_in[15], (const float*)d_in[16], (const float*)d_in[17],
        (const float*)d_in[18], (const float*)d_in[19], (const float*)d_in[20], (const float*)d_in[21],
        (float*)d_out);
}